// Round 2
// baseline (475.463 us; speedup 1.0000x reference)
//
#include <hip/hip_runtime.h>
#include <math.h>

#define N 2048
#define D 256
#define H 8
#define DK 32
#define L 4
#define DFF 1024
#define NEDGE 5
#define JC 4  // attention j-chunks (flash-decode split)

typedef short short8 __attribute__((ext_vector_type(8)));
typedef float floatx4 __attribute__((ext_vector_type(4)));

// Q pre-scale: 1/sqrt(DK) * log2(e)  (folded so attention uses raw v_exp_f32 = exp2)
#define QSCALE 0.25503485657f
#define LOG2E 1.4426950408889634f

#define MFMA(a, b, c) __builtin_amdgcn_mfma_f32_16x16x32_bf16(a, b, c, 0, 0, 0)

__device__ __forceinline__ unsigned short f2bf(float f) {
  unsigned int u = __float_as_uint(f);
  u += 0x7fffu + ((u >> 16) & 1u);
  return (unsigned short)(u >> 16);
}

__device__ __forceinline__ float exp2_hw(float x) {
  float r;
  asm("v_exp_f32 %0, %1" : "=v"(r) : "v"(x));
  return r;
}

// ---- setup: e8 permute + all weight transposes, one launch ----------------
// blocks [0,4096): eidx int32 -> packed uint8, permuted per 64-col group so
//   word g*16+c holds bytes for cols g*64 + {0,16,32,48} + c.
// blocks [4096,5120): Wq/Wk/Wv/Wo (D,D) -> bf16 (D,D)^T into wqkvb/wob
// blocks [5120,6144): W1 (D,DFF) -> (DFF,D)   blocks [6144,7168): W2 -> (D,DFF)
__global__ __launch_bounds__(256) void k_setup(
    const int* __restrict__ eidx, unsigned int* __restrict__ e8,
    const float* __restrict__ Wq, const float* __restrict__ Wk,
    const float* __restrict__ Wv, const float* __restrict__ Wo,
    const float* __restrict__ W1, const float* __restrict__ W2,
    unsigned short* __restrict__ wqkvb, unsigned short* __restrict__ wob,
    unsigned short* __restrict__ w1b, unsigned short* __restrict__ w2b) {
  __shared__ float t[32][33];
  const int blk = blockIdx.x;
  const int tid = threadIdx.x;
  if (blk < 4096) {
    int i = blk * 256 + tid;
    int r = i >> 9, u = i & 511, g = u >> 4, c = u & 15;
    const int* base = eidx + (size_t)r * N + g * 64 + c;
    e8[i] = (unsigned int)(base[0] & 0xff) |
            ((unsigned int)(base[16] & 0xff) << 8) |
            ((unsigned int)(base[32] & 0xff) << 16) |
            ((unsigned int)(base[48] & 0xff) << 24);
    return;
  }
  const int tx = tid & 31, ty = tid >> 5;
  const float* s;
  unsigned short* d;
  int rowOff, K_, N_, bx, by;
  if (blk < 5120) {
    int b2 = blk - 4096, z = b2 >> 6, rem = b2 & 63;
    int which = z >> 2, l = z & 3;
    s = (which == 0 ? Wq : which == 1 ? Wk : which == 2 ? Wv : Wo) + (size_t)l * D * D;
    if (which < 3) { d = wqkvb + (size_t)l * 768 * D; rowOff = which * 256; }
    else           { d = wob + (size_t)l * D * D;     rowOff = 0; }
    K_ = D; N_ = D; bx = rem & 7; by = rem >> 3;
  } else if (blk < 6144) {
    int b3 = blk - 5120, l = b3 >> 8, rem = b3 & 255;
    s = W1 + (size_t)l * D * DFF; d = w1b + (size_t)l * DFF * D; rowOff = 0;
    K_ = D; N_ = DFF; bx = rem & 31; by = rem >> 5;
  } else {
    int b4 = blk - 6144, l = b4 >> 8, rem = b4 & 255;
    s = W2 + (size_t)l * DFF * D; d = w2b + (size_t)l * D * DFF; rowOff = 0;
    K_ = DFF; N_ = D; bx = rem & 7; by = rem >> 3;
  }
  int n0 = bx * 32, k0 = by * 32;
#pragma unroll
  for (int i = 0; i < 32; i += 8) t[ty + i][tx] = s[(size_t)(k0 + ty + i) * N_ + n0 + tx];
  __syncthreads();
#pragma unroll
  for (int i = 0; i < 32; i += 8)
    d[(size_t)(rowOff + n0 + ty + i) * K_ + k0 + tx] = f2bf(t[tx][ty + i]);
}

// ---- shared qkv GEMM tail: x2 bf16 in Ab (stride 272) -> qb,kb,vtb --------
__device__ __forceinline__ void qkv_from_Ab(
    const unsigned short* Ab, const unsigned short* __restrict__ wqkv,
    unsigned short* __restrict__ qb, unsigned short* __restrict__ kb,
    unsigned short* __restrict__ vtb, int r0, int w, int quad, int c16) {
  short8 af[8];
#pragma unroll
  for (int k = 0; k < 8; ++k)
    af[k] = *(const short8*)&Ab[c16 * 272 + k * 32 + quad * 8];
#pragma unroll
  for (int tp = 0; tp < 3; ++tp) {  // tiles 6w+2tp, 6w+2tp+1
    const int cb0 = (w * 6 + tp * 2) * 16 + c16;
    const int cb1 = cb0 + 16;
    const unsigned short* B0 = wqkv + (size_t)cb0 * D + quad * 8;
    const unsigned short* B1 = wqkv + (size_t)cb1 * D + quad * 8;
    floatx4 a0 = {0.f, 0.f, 0.f, 0.f}, a1 = {0.f, 0.f, 0.f, 0.f};
#pragma unroll
    for (int k = 0; k < 8; ++k) {
      a0 = MFMA(af[k], *(const short8*)(B0 + k * 32), a0);
      a1 = MFMA(af[k], *(const short8*)(B1 + k * 32), a1);
    }
#pragma unroll
    for (int e = 0; e < 4; ++e) {
      const int grow = r0 + quad * 4 + e;
      float v0 = a0[e], v1 = a1[e];
#pragma unroll
      for (int half = 0; half < 2; ++half) {
        int gc = half ? cb1 : cb0;
        float v = half ? v1 : v0;
        if (gc < 256)      qb[(size_t)grow * D + gc] = f2bf(v * QSCALE);
        else if (gc < 512) kb[(size_t)grow * D + (gc - 256)] = f2bf(v);
        else               vtb[(size_t)(gc - 512) * N + grow] = f2bf(v);
      }
    }
  }
}

// ---- embed + layer-0 QKV --------------------------------------------------
__global__ __launch_bounds__(512) void k_embed_qkv(
    const int* __restrict__ nt, const float* __restrict__ emb,
    const unsigned short* __restrict__ wqkv0, float* __restrict__ x,
    unsigned short* __restrict__ qb, unsigned short* __restrict__ kb,
    unsigned short* __restrict__ vtb) {
  __shared__ __align__(16) unsigned short Ab[16 * 272];
  const int tid = threadIdx.x;
  const int w = tid >> 6, lane = tid & 63, quad = lane >> 4, c16 = lane & 15;
  const int r0 = blockIdx.x * 16;
  {
    const int r = tid >> 5, cb = (tid & 31) * 8;
    const int ty = nt[r0 + r];
    float4 a = *(const float4*)&emb[(size_t)ty * D + cb];
    float4 b = *(const float4*)&emb[(size_t)ty * D + cb + 4];
    *(float4*)&x[(size_t)(r0 + r) * D + cb] = a;
    *(float4*)&x[(size_t)(r0 + r) * D + cb + 4] = b;
    Ab[r * 272 + cb + 0] = f2bf(a.x); Ab[r * 272 + cb + 1] = f2bf(a.y);
    Ab[r * 272 + cb + 2] = f2bf(a.z); Ab[r * 272 + cb + 3] = f2bf(a.w);
    Ab[r * 272 + cb + 4] = f2bf(b.x); Ab[r * 272 + cb + 5] = f2bf(b.y);
    Ab[r * 272 + cb + 6] = f2bf(b.z); Ab[r * 272 + cb + 7] = f2bf(b.w);
  }
  __syncthreads();
  qkv_from_Ab(Ab, wqkv0, qb, kb, vtb, r0, w, quad, c16);
}

// ---- MFMA flash attention, j-split partials, fixed m=0 (unchanged) --------
#define PB_STR 72
__global__ __launch_bounds__(512) void k_attn(const unsigned short* __restrict__ qb,
                                              const unsigned short* __restrict__ kb,
                                              const unsigned short* __restrict__ vt,
                                              const unsigned int* __restrict__ e8,
                                              const float* __restrict__ eb,
                                              float* __restrict__ Opart,
                                              float* __restrict__ lpart) {
  __shared__ __align__(16) unsigned short Pb[H][16 * PB_STR];
  __shared__ float ebh[H][NEDGE];
  __shared__ unsigned int e8s[16][129];
  const int tid = threadIdx.x;
  const int h = tid >> 6;
  const int lane = tid & 63;
  const int quad = lane >> 4;
  const int c16 = lane & 15;
  const int r0 = blockIdx.x * 16;
  const int jc = blockIdx.y;

  if (tid < NEDGE * H) ebh[tid % H][tid / H] = eb[tid] * LOG2E;
  for (int t = tid; t < 16 * 128; t += 512) {
    int r = t >> 7, ww = t & 127;
    e8s[r][ww] = e8[(size_t)(r0 + r) * (N / 4) + jc * 128 + ww];
  }
  __syncthreads();

  short8 aq = *(const short8*)&qb[(size_t)(r0 + c16) * D + h * DK + quad * 8];

  float lrow[4] = {0.f, 0.f, 0.f, 0.f};
  floatx4 O0 = {0.f, 0.f, 0.f, 0.f};
  floatx4 O1 = {0.f, 0.f, 0.f, 0.f};

  for (int jj0 = 0; jj0 < N / JC; jj0 += 64) {
    const int j0 = jc * (N / JC) + jj0;
    const int g = jj0 >> 6;
    unsigned int wrd[4];
#pragma unroll
    for (int e = 0; e < 4; ++e) wrd[e] = e8s[quad * 4 + e][g * 16 + c16];

    floatx4 Sc[4];
#pragma unroll
    for (int t = 0; t < 4; ++t) {
      floatx4 cb;
#pragma unroll
      for (int e = 0; e < 4; ++e) cb[e] = ebh[h][(wrd[e] >> (8 * t)) & 0xff];
      short8 bk = *(const short8*)&kb[(size_t)(j0 + t * 16 + c16) * D + h * DK + quad * 8];
      Sc[t] = MFMA(aq, bk, cb);
    }
    float p[4][4];
#pragma unroll
    for (int e = 0; e < 4; ++e) {
#pragma unroll
      for (int t = 0; t < 4; ++t) p[t][e] = exp2_hw(Sc[t][e]);
      lrow[e] += (p[0][e] + p[1][e]) + (p[2][e] + p[3][e]);
    }
#pragma unroll
    for (int t = 0; t < 4; ++t)
#pragma unroll
      for (int e = 0; e < 4; ++e)
        Pb[h][(quad * 4 + e) * PB_STR + t * 16 + c16] = f2bf(p[t][e]);
    asm volatile("" ::: "memory");
#pragma unroll
    for (int jj = 0; jj < 2; ++jj) {
      short8 ap = *(const short8*)&Pb[h][c16 * PB_STR + jj * 32 + quad * 8];
      short8 bv0 = *(const short8*)&vt[(size_t)(h * DK + c16) * N + j0 + jj * 32 + quad * 8];
      short8 bv1 = *(const short8*)&vt[(size_t)(h * DK + 16 + c16) * N + j0 + jj * 32 + quad * 8];
      O0 = MFMA(ap, bv0, O0);
      O1 = MFMA(ap, bv1, O1);
    }
    asm volatile("" ::: "memory");
  }

#pragma unroll
  for (int e = 0; e < 4; ++e) {
    float v = lrow[e];
    v += __shfl_xor(v, 1); v += __shfl_xor(v, 2);
    v += __shfl_xor(v, 4); v += __shfl_xor(v, 8);
    lrow[e] = v;
  }
#pragma unroll
  for (int e = 0; e < 4; ++e) {
    int row = r0 + quad * 4 + e;
    size_t ob = ((size_t)jc * N + row) * D + h * DK;
    Opart[ob + c16] = O0[e];
    Opart[ob + 16 + c16] = O1[e];
    if (c16 == 0) lpart[((size_t)jc * N + row) * H + h] = lrow[e];
  }
}

// ---- fused layer tail: comb -> out-proj -> LN1 -> FFN -> LN2 -> next QKV --
// grid 128 blocks x 512 thr; block owns 16 rows end-to-end. Wave w owns
// col-slice 32w.. (256-wide GEMMs), 128w.. (FFN1). LDS A/H strides 272/1040
// bf16 keep ds_read_b128 fragment starts uniform over bank columns.
__global__ __launch_bounds__(512) void k_layer(
    const float* __restrict__ Opart, const float* __restrict__ lpart,
    float* __restrict__ x,
    const unsigned short* __restrict__ wo, const float* __restrict__ bo,
    const float* __restrict__ g1, const float* __restrict__ be1,
    const unsigned short* __restrict__ w1, const float* __restrict__ b1,
    const unsigned short* __restrict__ w2, const float* __restrict__ b2,
    const float* __restrict__ g2, const float* __restrict__ be2,
    const unsigned short* __restrict__ wqkvn,
    unsigned short* __restrict__ qb, unsigned short* __restrict__ kb,
    unsigned short* __restrict__ vtb,
    float* __restrict__ ppool) {
  __shared__ __align__(16) float Xr[16][260];
  __shared__ __align__(16) unsigned short Ab[16 * 272];
  __shared__ __align__(16) unsigned short Hs[16 * 1040];
  __shared__ float red1[8][16], red2[8][16], mu[16], rsg[16];

  const int tid = threadIdx.x;
  const int w = tid >> 6, lane = tid & 63, quad = lane >> 4, c16 = lane & 15;
  const int r0 = blockIdx.x * 16;

  // P0: residual rows + combine attention partials -> Ab bf16
  {
    const int r = tid >> 5, cb = (tid & 31) * 8;
    *(float4*)&Xr[r][cb] = *(const float4*)&x[(size_t)(r0 + r) * D + cb];
    *(float4*)&Xr[r][cb + 4] = *(const float4*)&x[(size_t)(r0 + r) * D + cb + 4];
    const int hh = cb >> 5;
    float lsum = 0.f;
    float o[8] = {0.f, 0.f, 0.f, 0.f, 0.f, 0.f, 0.f, 0.f};
#pragma unroll
    for (int c = 0; c < JC; ++c) {
      lsum += lpart[((size_t)c * N + r0 + r) * H + hh];
      const float* op = &Opart[((size_t)c * N + r0 + r) * D + cb];
      float4 p0 = *(const float4*)op;
      float4 p1 = *(const float4*)(op + 4);
      o[0] += p0.x; o[1] += p0.y; o[2] += p0.z; o[3] += p0.w;
      o[4] += p1.x; o[5] += p1.y; o[6] += p1.z; o[7] += p1.w;
    }
    const float inv = 1.f / lsum;
#pragma unroll
    for (int j = 0; j < 8; ++j) Ab[r * 272 + cb + j] = f2bf(o[j] * inv);
  }
  __syncthreads();

  short8 af[8];
  // ---- GEMM1: out-proj (Nn=256, K=256); + bo + residual -> LN1 ----
#pragma unroll
  for (int k = 0; k < 8; ++k)
    af[k] = *(const short8*)&Ab[c16 * 272 + k * 32 + quad * 8];
  floatx4 A0 = {0.f, 0.f, 0.f, 0.f}, A1 = {0.f, 0.f, 0.f, 0.f};
  {
    const unsigned short* B0 = wo + (size_t)(w * 32 + c16) * D + quad * 8;
    const unsigned short* B1 = wo + (size_t)(w * 32 + 16 + c16) * D + quad * 8;
#pragma unroll
    for (int k = 0; k < 8; ++k) {
      A0 = MFMA(af[k], *(const short8*)(B0 + k * 32), A0);
      A1 = MFMA(af[k], *(const short8*)(B1 + k * 32), A1);
    }
  }
  float v0[4], v1[4];
  const int col0 = w * 32 + c16, col1 = w * 32 + 16 + c16;
#pragma unroll
  for (int e = 0; e < 4; ++e) {
    const int row = quad * 4 + e;
    v0[e] = A0[e] + bo[col0] + Xr[row][col0];
    v1[e] = A1[e] + bo[col1] + Xr[row][col1];
    float pe = v0[e] + v1[e];
    float qe = v0[e] * v0[e] + v1[e] * v1[e];
    pe += __shfl_xor(pe, 1); pe += __shfl_xor(pe, 2);
    pe += __shfl_xor(pe, 4); pe += __shfl_xor(pe, 8);
    qe += __shfl_xor(qe, 1); qe += __shfl_xor(qe, 2);
    qe += __shfl_xor(qe, 4); qe += __shfl_xor(qe, 8);
    if (c16 == 0) { red1[w][row] = pe; red2[w][row] = qe; }
  }
  __syncthreads();
  if (tid < 16) {
    float m = 0.f, q = 0.f;
#pragma unroll
    for (int ww = 0; ww < 8; ++ww) { m += red1[ww][tid]; q += red2[ww][tid]; }
    m *= (1.f / 256.f);
    q = q * (1.f / 256.f) - m * m;
    mu[tid] = m;
    rsg[tid] = rsqrtf(q + 1e-5f);
  }
  __syncthreads();
#pragma unroll
  for (int e = 0; e < 4; ++e) {
    const int row = quad * 4 + e;
    float o0 = (v0[e] - mu[row]) * rsg[row] * g1[col0] + be1[col0];
    float o1 = (v1[e] - mu[row]) * rsg[row] * g1[col1] + be1[col1];
    Xr[row][col0] = o0; Xr[row][col1] = o1;            // Xr now holds x1
    Ab[row * 272 + col0] = f2bf(o0);
    Ab[row * 272 + col1] = f2bf(o1);
  }
  __syncthreads();

  // ---- GEMM2: FFN1 (Nn=1024, K=256) + gelu -> Hs ----
#pragma unroll
  for (int k = 0; k < 8; ++k)
    af[k] = *(const short8*)&Ab[c16 * 272 + k * 32 + quad * 8];
#pragma unroll
  for (int tp = 0; tp < 4; ++tp) {
    const int cb0 = w * 128 + tp * 32 + c16;
    const int cb1 = cb0 + 16;
    const unsigned short* B0 = w1 + (size_t)cb0 * D + quad * 8;
    const unsigned short* B1 = w1 + (size_t)cb1 * D + quad * 8;
    floatx4 a0 = {0.f, 0.f, 0.f, 0.f}, a1 = {0.f, 0.f, 0.f, 0.f};
#pragma unroll
    for (int k = 0; k < 8; ++k) {
      a0 = MFMA(af[k], *(const short8*)(B0 + k * 32), a0);
      a1 = MFMA(af[k], *(const short8*)(B1 + k * 32), a1);
    }
#pragma unroll
    for (int e = 0; e < 4; ++e) {
      const int row = quad * 4 + e;
      float h0 = a0[e] + b1[cb0];
      float h1 = a1[e] + b1[cb1];
      h0 = 0.5f * h0 * (1.0f + erff(h0 * 0.70710678118654752f));
      h1 = 0.5f * h1 * (1.0f + erff(h1 * 0.70710678118654752f));
      Hs[row * 1040 + cb0] = f2bf(h0);
      Hs[row * 1040 + cb1] = f2bf(h1);
    }
  }
  __syncthreads();

  // ---- GEMM3: FFN2 (Nn=256, K=1024); + b2 + residual(x1) -> LN2 ----
  floatx4 C0 = {0.f, 0.f, 0.f, 0.f}, C1 = {0.f, 0.f, 0.f, 0.f};
  {
    const unsigned short* B0 = w2 + (size_t)col0 * DFF + quad * 8;
    const unsigned short* B1 = w2 + (size_t)col1 * DFF + quad * 8;
#pragma unroll
    for (int k = 0; k < 32; ++k) {
      short8 a = *(const short8*)&Hs[c16 * 1040 + k * 32 + quad * 8];
      C0 = MFMA(a, *(const short8*)(B0 + k * 32), C0);
      C1 = MFMA(a, *(const short8*)(B1 + k * 32), C1);
    }
  }
#pragma unroll
  for (int e = 0; e < 4; ++e) {
    const int row = quad * 4 + e;
    v0[e] = C0[e] + b2[col0] + Xr[row][col0];
    v1[e] = C1[e] + b2[col1] + Xr[row][col1];
    float pe = v0[e] + v1[e];
    float qe = v0[e] * v0[e] + v1[e] * v1[e];
    pe += __shfl_xor(pe, 1); pe += __shfl_xor(pe, 2);
    pe += __shfl_xor(pe, 4); pe += __shfl_xor(pe, 8);
    qe += __shfl_xor(qe, 1); qe += __shfl_xor(qe, 2);
    qe += __shfl_xor(qe, 4); qe += __shfl_xor(qe, 8);
    if (c16 == 0) { red1[w][row] = pe; red2[w][row] = qe; }
  }
  __syncthreads();
  if (tid < 16) {
    float m = 0.f, q = 0.f;
#pragma unroll
    for (int ww = 0; ww < 8; ++ww) { m += red1[ww][tid]; q += red2[ww][tid]; }
    m *= (1.f / 256.f);
    q = q * (1.f / 256.f) - m * m;
    mu[tid] = m;
    rsg[tid] = rsqrtf(q + 1e-5f);
  }
  __syncthreads();

  if (!ppool) {
#pragma unroll
    for (int e = 0; e < 4; ++e) {
      const int row = quad * 4 + e;
      float o0 = (v0[e] - mu[row]) * rsg[row] * g2[col0] + be2[col0];
      float o1 = (v1[e] - mu[row]) * rsg[row] * g2[col1] + be2[col1];
      x[(size_t)(r0 + row) * D + col0] = o0;
      x[(size_t)(r0 + row) * D + col1] = o1;
      Ab[row * 272 + col0] = f2bf(o0);
      Ab[row * 272 + col1] = f2bf(o1);
    }
    __syncthreads();
    // ---- GEMM4: next-layer QKV ----
    qkv_from_Ab(Ab, wqkvn, qb, kb, vtb, r0, w, quad, c16);
  } else {
    // last layer: per-block pool partials (sum over 16 rows, max over 16 rows)
    float s0 = 0.f, s1 = 0.f, m0 = -INFINITY, m1 = -INFINITY;
#pragma unroll
    for (int e = 0; e < 4; ++e) {
      const int row = quad * 4 + e;
      float o0 = (v0[e] - mu[row]) * rsg[row] * g2[col0] + be2[col0];
      float o1 = (v1[e] - mu[row]) * rsg[row] * g2[col1] + be2[col1];
      s0 += o0; s1 += o1;
      m0 = fmaxf(m0, o0); m1 = fmaxf(m1, o1);
    }
    s0 += __shfl_xor(s0, 16); s0 += __shfl_xor(s0, 32);
    s1 += __shfl_xor(s1, 16); s1 += __shfl_xor(s1, 32);
    m0 = fmaxf(m0, __shfl_xor(m0, 16)); m0 = fmaxf(m0, __shfl_xor(m0, 32));
    m1 = fmaxf(m1, __shfl_xor(m1, 16)); m1 = fmaxf(m1, __shfl_xor(m1, 32));
    if (quad == 0) {
      float* pp = ppool + (size_t)blockIdx.x * 512;
      pp[col0] = s0; pp[col1] = s1;
      pp[256 + col0] = m0; pp[256 + col1] = m1;
    }
  }
}

// ---- pool phase 2: reduce 128 partials + project ---------------------------
__global__ __launch_bounds__(256) void k_pool2(const float* __restrict__ part,
                                               const float* __restrict__ Wr,
                                               const float* __restrict__ br,
                                               float* __restrict__ out) {
  __shared__ float pooled[2 * D];
  int d = threadIdx.x;
  float sum = 0.f, mx = -INFINITY;
  for (int b = 0; b < 128; ++b) {
    sum += part[(size_t)b * 512 + d];
    mx = fmaxf(mx, part[(size_t)b * 512 + 256 + d]);
  }
  pooled[d] = sum * (1.0f / N);
  pooled[D + d] = mx;
  __syncthreads();
  float acc = br[d];
  for (int k2 = 0; k2 < 2 * D; ++k2) acc = fmaf(pooled[k2], Wr[(size_t)k2 * D + d], acc);
  out[d] = acc;
}

extern "C" void kernel_launch(void* const* d_in, const int* in_sizes, int n_in,
                              void* d_out, int out_size, void* d_ws, size_t ws_size,
                              hipStream_t stream) {
  const int* node_types = (const int*)d_in[0];
  const int* eidx = (const int*)d_in[1];
  const float* node_emb = (const float*)d_in[2];
  const float* Wq = (const float*)d_in[3];
  const float* Wk = (const float*)d_in[4];
  const float* Wv = (const float*)d_in[5];
  const float* Wo = (const float*)d_in[6];
  const float* bo = (const float*)d_in[7];
  const float* eb = (const float*)d_in[8];
  const float* W1 = (const float*)d_in[9];
  const float* b1 = (const float*)d_in[10];
  const float* W2 = (const float*)d_in[11];
  const float* b2 = (const float*)d_in[12];
  const float* g1 = (const float*)d_in[13];
  const float* be1 = (const float*)d_in[14];
  const float* g2 = (const float*)d_in[15];
  const float* be2 = (const float*)d_in[16];
  const float* Wr = (const float*)d_in[17];
  const float* br = (const float*)d_in[18];
  float* out = (float*)d_out;

  // workspace layout
  float* x = (float*)d_ws;                       // N*D fp32
  float* Opart = x + (size_t)N * D;              // JC*N*D fp32
  float* lpart = Opart + (size_t)JC * N * D;     // JC*N*H
  float* ppool = lpart + (size_t)JC * N * H;     // 128*512
  unsigned short* qb = (unsigned short*)(ppool + 128 * 512);
  unsigned short* kb = qb + (size_t)N * D;
  unsigned short* vtb = kb + (size_t)N * D;      // (D, N) head-major d
  unsigned short* wqkvb = vtb + (size_t)N * D;   // L x (768, 256)
  unsigned short* wob = wqkvb + (size_t)L * 768 * D;
  unsigned short* w1b = wob + (size_t)L * D * D;
  unsigned short* w2b = w1b + (size_t)L * DFF * D;
  unsigned int* e8 = (unsigned int*)(w2b + (size_t)L * D * DFF);  // N*N bytes

  k_setup<<<7168, 256, 0, stream>>>(eidx, e8, Wq, Wk, Wv, Wo, W1, W2,
                                    wqkvb, wob, w1b, w2b);
  k_embed_qkv<<<128, 512, 0, stream>>>(node_types, node_emb, wqkvb, x, qb, kb, vtb);

  for (int l = 0; l < L; ++l) {
    k_attn<<<dim3(N / 16, JC), 512, 0, stream>>>(qb, kb, vtb, e8,
                                                 eb + (size_t)l * NEDGE * H,
                                                 Opart, lpart);
    k_layer<<<128, 512, 0, stream>>>(
        Opart, lpart, x,
        wob + (size_t)l * D * D, bo + (size_t)l * D,
        g1 + (size_t)l * D, be1 + (size_t)l * D,
        w1b + (size_t)l * DFF * D, b1 + (size_t)l * DFF,
        w2b + (size_t)l * D * DFF, b2 + (size_t)l * D,
        g2 + (size_t)l * D, be2 + (size_t)l * D,
        (l < L - 1) ? wqkvb + (size_t)(l + 1) * 768 * D : nullptr,
        qb, kb, vtb,
        (l == L - 1) ? ppool : nullptr);
  }

  k_pool2<<<1, 256, 0, stream>>>(ppool, Wr, br, out);
}